// Round 1
// baseline (210.287 us; speedup 1.0000x reference)
//
#include <hip/hip_runtime.h>

// Integrator (scaling & squaring) for vel [16,2,512,512] f32, with logdet-Jacobian.
// Layout: planar [N,C,H,W] f32 everywhere.
// Ping-pong: init -> ws ; steps alternate ws<->d_out ; 7th step lands in d_out.
// ws requirement: (8388608 + 4194304) * 4 = 48 MiB.

#define NB 16
#define HH 512
#define WW 512
#define HW (HH * WW)          // 262144 = 1<<18
#define TOT (NB * HW)         // 4194304
#define EPS 0.0078125f        // 2^-7
#define DISP_ELEMS (NB * 2 * HW)   // 8388608

struct Samp {
    int i00, i01, i10, i11;   // clamped plane offsets (y*W+x)
    float w00, w01, w10, w11; // bilinear weights with OOB folded to 0
};

__device__ __forceinline__ Samp make_samp(float sy, float sx) {
    float fy = floorf(sy), fx = floorf(sx);
    float wy = sy - fy, wx = sx - fx;
    int y0 = (int)fy, x0 = (int)fx;
    int y1 = y0 + 1, x1 = x0 + 1;
    bool xv0 = (unsigned)x0 < (unsigned)WW;
    bool xv1 = (unsigned)x1 < (unsigned)WW;
    bool yv0 = (unsigned)y0 < (unsigned)HH;
    bool yv1 = (unsigned)y1 < (unsigned)HH;
    int xc0 = min(max(x0, 0), WW - 1), xc1 = min(max(x1, 0), WW - 1);
    int yc0 = min(max(y0, 0), HH - 1), yc1 = min(max(y1, 0), HH - 1);
    Samp s;
    s.i00 = yc0 * WW + xc0; s.i01 = yc0 * WW + xc1;
    s.i10 = yc1 * WW + xc0; s.i11 = yc1 * WW + xc1;
    float omwx = 1.0f - wx, omwy = 1.0f - wy;
    s.w00 = (xv0 && yv0) ? omwx * omwy : 0.0f;
    s.w01 = (xv1 && yv0) ? wx * omwy   : 0.0f;
    s.w10 = (xv0 && yv1) ? omwx * wy   : 0.0f;
    s.w11 = (xv1 && yv1) ? wx * wy     : 0.0f;
    return s;
}

// init: disp0 = eps*vel ; ldjac0 = -sum_n (-eps)^n tr(J^n)/n  (J = sobel jacobian of vel)
__global__ void __launch_bounds__(256) init_kernel(const float* __restrict__ vel,
                                                   float* __restrict__ ddst,
                                                   float* __restrict__ ldst) {
    int idx = blockIdx.x * 256 + threadIdx.x;
    if (idx >= TOT) return;
    int n = idx >> 18;
    int rem = idx & (HW - 1);
    int y = rem >> 9, x = rem & (WW - 1);

    const float* v0 = vel + (size_t)n * 2 * HW;  // vel channel 0 (y-vel)
    const float* v1 = v0 + HW;                   // vel channel 1 (x-vel)

    float c0 = v0[rem], c1 = v1[rem];
    ddst[(size_t)n * 2 * HW + rem] = EPS * c0;
    ddst[(size_t)n * 2 * HW + HW + rem] = EPS * c1;

    // 3x3 neighborhood, replicate padding
    int ym = max(y - 1, 0), yp = min(y + 1, HH - 1);
    int xm = max(x - 1, 0), xp = min(x + 1, WW - 1);
    int rmm = ym * WW + xm, rm0 = ym * WW + x, rmp = ym * WW + xp;
    int r0m = y * WW + xm,                    r0p = y * WW + xp;
    int rpm = yp * WW + xm, rp0 = yp * WW + x, rpp = yp * WW + xp;

    // sobel (cross-correlation, scaled by 0.125)
    // dy = [[-1,-2,-1],[0,0,0],[1,2,1]], dx = [[-1,0,1],[-2,0,2],[-1,0,1]]
    float a, b, c, d;
    {
        float tmm = v0[rmm], tm0 = v0[rm0], tmp = v0[rmp];
        float t0m = v0[r0m],                t0p = v0[r0p];
        float tpm = v0[rpm], tp0 = v0[rp0], tpp = v0[rpp];
        a = 0.125f * ((tpm + 2.0f * tp0 + tpp) - (tmm + 2.0f * tm0 + tmp)); // d vel_y / dy
        b = 0.125f * ((tmp + 2.0f * t0p + tpp) - (tmm + 2.0f * t0m + tpm)); // d vel_y / dx
    }
    {
        float tmm = v1[rmm], tm0 = v1[rm0], tmp = v1[rmp];
        float t0m = v1[r0m],                t0p = v1[r0p];
        float tpm = v1[rpm], tp0 = v1[rp0], tpp = v1[rpp];
        c = 0.125f * ((tpm + 2.0f * tp0 + tpp) - (tmm + 2.0f * tm0 + tmp)); // d vel_x / dy
        d = 0.125f * ((tmp + 2.0f * t0p + tpp) - (tmm + 2.0f * t0m + tpm)); // d vel_x / dx
    }

    // ld = eps*tr1 - eps^2/2*tr2 + eps^3/3*tr3 - eps^4/4*tr4, via explicit 2x2 powers
    float xa = a, xb = b, xc = c, xd = d;
    float ld = EPS * (xa + xd);
    // n=2: X = X*J
    float na = xa * a + xb * c, nb = xa * b + xb * d;
    float nc = xc * a + xd * c, nd = xc * b + xd * d;
    xa = na; xb = nb; xc = nc; xd = nd;
    ld -= (EPS * EPS) * (xa + xd) * 0.5f;
    // n=3
    na = xa * a + xb * c; nb = xa * b + xb * d;
    nc = xc * a + xd * c; nd = xc * b + xd * d;
    xa = na; xb = nb; xc = nc; xd = nd;
    ld += (EPS * EPS * EPS) * (xa + xd) * (1.0f / 3.0f);
    // n=4 (trace only)
    na = xa * a + xb * c;
    nd = xc * b + xd * d;
    ld -= (EPS * EPS * EPS * EPS) * (na + nd) * 0.25f;

    ldst[(size_t)n * HW + rem] = ld;
}

// one composition step, fused disp + ldjac update:
//   disp_new(p)  = disp(p)  + bilerp(disp,  p + disp(p))
//   ldjac_new(p) = ldjac(p) + bilerp(ldjac, p + disp_new(p))
__global__ void __launch_bounds__(256) step_kernel(const float* __restrict__ dsrc,
                                                   const float* __restrict__ lsrc,
                                                   float* __restrict__ ddst,
                                                   float* __restrict__ ldst) {
    int idx = blockIdx.x * 256 + threadIdx.x;
    if (idx >= TOT) return;
    int n = idx >> 18;
    int rem = idx & (HW - 1);
    int y = rem >> 9, x = rem & (WW - 1);

    const float SCY = 512.0f / 511.0f;
    const float SCX = 512.0f / 511.0f;

    const float* dy_p = dsrc + (size_t)n * 2 * HW;
    const float* dx_p = dy_p + HW;
    float d0 = dy_p[rem], d1 = dx_p[rem];

    float sy = ((float)y + d0) * SCY - 0.5f;
    float sx = ((float)x + d1) * SCX - 0.5f;
    Samp s = make_samp(sy, sx);

    float nd0 = d0 + s.w00 * dy_p[s.i00] + s.w01 * dy_p[s.i01]
                   + s.w10 * dy_p[s.i10] + s.w11 * dy_p[s.i11];
    float nd1 = d1 + s.w00 * dx_p[s.i00] + s.w01 * dx_p[s.i01]
                   + s.w10 * dx_p[s.i10] + s.w11 * dx_p[s.i11];

    ddst[(size_t)n * 2 * HW + rem] = nd0;
    ddst[(size_t)n * 2 * HW + HW + rem] = nd1;

    // ldjac sampled with the NEW disp at this pixel
    float sy2 = ((float)y + nd0) * SCY - 0.5f;
    float sx2 = ((float)x + nd1) * SCX - 0.5f;
    Samp s2 = make_samp(sy2, sx2);

    const float* l_p = lsrc + (size_t)n * HW;
    float l = l_p[rem];
    float nl = l + s2.w00 * l_p[s2.i00] + s2.w01 * l_p[s2.i01]
                 + s2.w10 * l_p[s2.i10] + s2.w11 * l_p[s2.i11];
    ldst[(size_t)n * HW + rem] = nl;
}

extern "C" void kernel_launch(void* const* d_in, const int* in_sizes, int n_in,
                              void* d_out, int out_size, void* d_ws, size_t ws_size,
                              hipStream_t stream) {
    const float* vel = (const float*)d_in[0];
    float* out = (float*)d_out;
    float* ws = (float*)d_ws;

    float* dispA = out;                    // d_out: disp (8388608 f32)
    float* ldjA  = out + DISP_ELEMS;       //        ldjac (4194304 f32)
    float* dispB = ws;                     // ws:   disp
    float* ldjB  = ws + DISP_ELEMS;        //       ldjac   (needs 48 MiB total)

    dim3 grid(TOT / 256), block(256);

    // init into B (ws); 7 steps alternate: s=0 -> A(d_out), s=1 -> B, ... s=6 -> A(d_out)
    init_kernel<<<grid, block, 0, stream>>>(vel, dispB, ldjB);

    const float* ds = dispB;
    const float* ls = ldjB;
    for (int s = 0; s < 7; ++s) {
        float* dd  = (s & 1) ? dispB : dispA;
        float* ldd = (s & 1) ? ldjB  : ldjA;
        step_kernel<<<grid, block, 0, stream>>>(ds, ls, dd, ldd);
        ds = dd; ls = ldd;
    }
}